// Round 5
// baseline (1309.291 us; speedup 1.0000x reference)
//
#include <hip/hip_runtime.h>

typedef _Float16 f16;
typedef _Float16 f16x8 __attribute__((ext_vector_type(8)));
typedef float f32x4 __attribute__((ext_vector_type(4)));

// dims
#define BB 16
#define TT 128
#define VV 32000
#define EE 400
#define HH 1150
#define MM 2048   // T*B rows

#define NWG1 72           // layer1 blocks (4608/64)
#define NWG2 144          // layer2 blocks (4608/32)
#define NWG3 26           // layer3 blocks (1664/64)
#define NWGT (NWG1+NWG2+NWG3)   // 242 <= 256 CUs -> 1 block/CU

__device__ __forceinline__ float sigm(float x){ return 1.f/(1.f + __expf(-x)); }
__device__ __forceinline__ float ftanh(float x){ return 2.f/(1.f + __expf(-2.f*x)) - 1.f; }

// Write-through (LLC-coherent) store for h-state: sc0+sc1 bypasses the
// per-XCD L2, so the freshly produced h lands at the LLC before the
// completion counter is bumped. Consumers use PLAIN CACHED loads: each
// hseq slot address is written exactly once and read only afterwards,
// so no XCD L2 can ever hold a stale copy -- first touch fetches the
// final data from LLC, peers on the XCD hit L2 (dedup, unlike round-4's
// sc1 loads which re-pulled ~14 MB/step from the LLC).
__device__ __forceinline__ void st2c(f16* p, f16 v){
    asm volatile("global_store_short %0, %1, off sc0 sc1"
                 :: "v"(p), "v"(v) : "memory");
}

// ---------------- conversion kernels ----------------

__global__ void conv_emb(const float* __restrict__ src, f16* __restrict__ dst){
    int v = blockIdx.y;
    int k = blockIdx.x*256 + threadIdx.x;
    if (k >= 416) return;
    float val = (k < EE) ? src[v*EE + k] : 0.f;
    dst[v*416 + k] = (f16)val;
}

__global__ void embed_gather(const float* __restrict__ emb, const int* __restrict__ x,
                             f16* __restrict__ dst){
    int m = blockIdx.y;            // t*16+b
    int k = blockIdx.x*256 + threadIdx.x;
    if (k >= 416) return;
    int t = m >> 4, b = m & 15;
    int row = x[b*TT + t];
    float val = (k < EE) ? emb[row*EE + k] : 0.f;
    dst[m*416 + k] = (f16)val;
}

// W (4*Hout, Ksrc) f32 -> dst (Np, Kp) f16, dst row n = j*4+g  <- src row g*Hout+j
__global__ void conv_w(const float* __restrict__ src, f16* __restrict__ dst,
                       int Hout, int Ksrc, int Kp){
    int n = blockIdx.y;
    int k = blockIdx.x*256 + threadIdx.x;
    if (k >= Kp) return;
    int j = n >> 2, g = n & 3;
    float val = (j < Hout && k < Ksrc) ? src[(g*Hout + j)*Ksrc + k] : 0.f;
    dst[(size_t)n*Kp + k] = (f16)val;
}

__global__ void conv_bias(const float* __restrict__ bi, const float* __restrict__ bh,
                          float* __restrict__ dst, int Hout, int Np){
    int n = blockIdx.x*256 + threadIdx.x;
    if (n >= Np) return;
    int j = n >> 2, g = n & 3;
    dst[n] = (j < Hout) ? (bi[g*Hout + j] + bh[g*Hout + j]) : 0.f;
}

// ---------------- GEMM: C(M,N) = A(M,Kp) * B(N,Kp)^T + bias ----------------
template<int SC>
__global__ __launch_bounds__(256) void gemm16(
    const f16* __restrict__ A, const f16* __restrict__ B,
    const float* __restrict__ bias, float* __restrict__ C,
    int Kp, int Nst)
{
    __shared__ __align__(16) f16 lA[128*32];
    __shared__ __align__(16) f16 lB[128*32];
    const int lane = threadIdx.x & 63;
    const int wid  = threadIdx.x >> 6;
    const int m0 = blockIdx.y * 128, n0 = blockIdx.x * 128;
    f32x4 acc[4][4] = {};
    const int sr = threadIdx.x >> 2;
    const int sc = (threadIdx.x & 3) * 8;
    for (int k0 = 0; k0 < Kp; k0 += 32) {
        __syncthreads();
        *(f16x8*)&lA[ sr      *32 + sc] = *(const f16x8*)&A[(size_t)(m0 + sr     )*Kp + k0 + sc];
        *(f16x8*)&lA[(sr + 64)*32 + sc] = *(const f16x8*)&A[(size_t)(m0 + sr + 64)*Kp + k0 + sc];
        *(f16x8*)&lB[ sr      *32 + sc] = *(const f16x8*)&B[(size_t)(n0 + sr     )*Kp + k0 + sc];
        *(f16x8*)&lB[(sr + 64)*32 + sc] = *(const f16x8*)&B[(size_t)(n0 + sr + 64)*Kp + k0 + sc];
        __syncthreads();
        const int wr = (wid >> 1) * 64, wc = (wid & 1) * 64;
        f16x8 af[4], bf[4];
        #pragma unroll
        for (int i = 0; i < 4; ++i)
            af[i] = *(const f16x8*)&lA[(wr + i*16 + (lane & 15))*32 + (lane >> 4)*8];
        #pragma unroll
        for (int j = 0; j < 4; ++j)
            bf[j] = *(const f16x8*)&lB[(wc + j*16 + (lane & 15))*32 + (lane >> 4)*8];
        #pragma unroll
        for (int i = 0; i < 4; ++i)
            #pragma unroll
            for (int j = 0; j < 4; ++j)
                acc[i][j] = __builtin_amdgcn_mfma_f32_16x16x32_f16(af[i], bf[j], acc[i][j], 0, 0, 0);
    }
    const int wr = (wid >> 1) * 64, wc = (wid & 1) * 64;
    #pragma unroll
    for (int i = 0; i < 4; ++i) {
        #pragma unroll
        for (int j = 0; j < 4; ++j) {
            int gc = n0 + wc + j*16 + (lane & 15);
            float bb = bias[gc];
            #pragma unroll
            for (int r = 0; r < 4; ++r) {
                int gr = m0 + wr + i*16 + (lane >> 4)*4 + r;
                float v = acc[i][j][r] + bb;
                if (SC) C[((size_t)(gr >> 7)*VV + gc)*TT + (gr & 127)] = v;   // out[b][v][t]
                else    C[(size_t)gr*Nst + gc] = v;
            }
        }
    }
}

// ---------------- dataflow-synchronized persistent 3-layer LSTM ----------------
// No global barrier. Each layer runs its own t-loop; readiness is tracked by
// per-(layer,t) completion counters at the LLC (agent-scope atomics).
//   L1 step t: wait cnt1[t]==72  (t>0)                 read hs1[t]  write hs1[t+1]
//   L2 step t: wait cnt1[t+1]==72 && cnt2[t]==144      read hs1[t+1], hs2[t] write hs2[t+1]
//   L3 step t: wait cnt2[t+1]==144 && cnt3[t]==26      read hs2[t+1], hs3[t] write hs3[t+1]
// h slots are write-once (fresh buffer per step) -> consumer loads are plain
// cached loads (XCD-L2 dedup); producer stores are sc0|sc1 write-through with
// vmcnt(0) + __syncthreads before the single per-block counter increment.

template<int KIH, int KHH, int NG>
__device__ __forceinline__ void lstm_role(
    float (&red)[4][16][66], float (&cst)[16][16],
    const float* __restrict__ pre,     // L1 only (KIH==0): (2048,4608) rows t*16+b, bias folded in
    const float* __restrict__ bias,    // L2/L3: packed (Np)
    const f16* __restrict__ Wih,       // (Np,1152) packed, KIH>0 only
    const f16* __restrict__ Whh,       // (Np,HpHH) packed
    const f16* __restrict__ xseq,      // producer h sequence base (slot stride 16*1152)
    f16* __restrict__ hseq,            // own h sequence base (slot stride 16*HpHH)
    f16* __restrict__ xs3,             // L3 only: (b*TT+t)*416+j
    float* __restrict__ hout, float* __restrict__ cout,
    const unsigned* __restrict__ cprod, unsigned* __restrict__ cown,
    int nprod, int nown, int bid, int H, int l3)
{
    constexpr int HpHH = KHH * 128;
    constexpr int SLO  = 16 * HpHH;    // own slot stride (elements)
    constexpr int SLP  = 16 * 1152;    // producer slot stride
    constexpr int KIHA = (KIH > 0) ? KIH : 1;
    constexpr int G = NG * 16;
    const int lane = threadIdx.x & 63, kw = threadIdx.x >> 6;
    const int n0 = bid * G;
    cst[threadIdx.x & 15][threadIdx.x >> 4] = 0.f;   // 256 threads cover 16x16
    const int arow = lane & 15, aoff = (lane >> 4) * 8;
    const size_t hofsHH = (size_t)arow * HpHH + kw * (KHH * 32) + aoff;
    const size_t hofsIH = (size_t)arow * 1152 + kw * 288 + aoff;

    // weight slices (normal cached loads; L2 stays warm -- no invalidates exist)
    f16x8 wh[NG][KHH];
    #pragma unroll
    for (int g = 0; g < NG; ++g) {
        const f16* wp = Whh + (size_t)(n0 + g*16 + arow) * HpHH + kw * (KHH*32) + aoff;
        #pragma unroll
        for (int i = 0; i < KHH; ++i) wh[g][i] = *(const f16x8*)(wp + i*32);
    }
    f16x8 wi[NG][KIHA];
    if constexpr (KIH > 0) {
        #pragma unroll
        for (int g = 0; g < NG; ++g) {
            const f16* wp = Wih + (size_t)(n0 + g*16 + arow) * 1152 + kw * 288 + aoff;
            #pragma unroll
            for (int i = 0; i < KIH; ++i) wi[g][i] = *(const f16x8*)(wp + i*32);
        }
    }
    const int b  = threadIdx.x & 15;
    const int jl = threadIdx.x >> 4;      // 0..(NG*4-1) in the update guard
    f32x4 bias4 = {0.f,0.f,0.f,0.f};
    if constexpr (KIH > 0) {
        if (threadIdx.x < NG*64) bias4 = *(const f32x4*)(bias + n0 + jl*4);
    }
    __syncthreads();

    for (int t = 0; t < TT; ++t) {
        f32x4 p4;
        if constexpr (KIH == 0) {           // L1: prefetch pre before the wait
            if (threadIdx.x < NG*64)
                p4 = *(const f32x4*)(pre + (size_t)(t*16 + b)*4608 + n0 + jl*4);
        }
        if (threadIdx.x == 0) {
            if constexpr (KIH > 0) {
                while (__hip_atomic_load((unsigned*)cprod + (size_t)(t+1)*16,
                                         __ATOMIC_RELAXED, __HIP_MEMORY_SCOPE_AGENT) < (unsigned)nprod)
                    __builtin_amdgcn_s_sleep(1);
            }
            if (t > 0) {
                while (__hip_atomic_load(cown + (size_t)t*16,
                                         __ATOMIC_RELAXED, __HIP_MEMORY_SCOPE_AGENT) < (unsigned)nown)
                    __builtin_amdgcn_s_sleep(1);
            }
        }
        __syncthreads();
        __builtin_amdgcn_sched_barrier(0);

        // plain cached loads of x/h (write-once slots: no stale-line hazard)
        f16x8 xv[KIHA], hv[KHH];
        if constexpr (KIH > 0) {
            const f16* xp = xseq + (size_t)(t+1)*SLP + hofsIH;   // producer h_t
            #pragma unroll
            for (int i = 0; i < KIH; ++i) xv[i] = *(const f16x8*)(xp + i*32);
        }
        const f16* hp = hseq + (size_t)t*SLO + hofsHH;
        #pragma unroll
        for (int i = 0; i < KHH; ++i) hv[i] = *(const f16x8*)(hp + i*32);

        f32x4 acc[NG] = {};
        if constexpr (KIH > 0) {
            #pragma unroll
            for (int i = 0; i < KIH; ++i)
                #pragma unroll
                for (int g = 0; g < NG; ++g)
                    acc[g] = __builtin_amdgcn_mfma_f32_16x16x32_f16(xv[i], wi[g][i], acc[g], 0, 0, 0);
        }
        #pragma unroll
        for (int i = 0; i < KHH; ++i)
            #pragma unroll
            for (int g = 0; g < NG; ++g)
                acc[g] = __builtin_amdgcn_mfma_f32_16x16x32_f16(hv[i], wh[g][i], acc[g], 0, 0, 0);

        #pragma unroll
        for (int g = 0; g < NG; ++g)
            #pragma unroll
            for (int r = 0; r < 4; ++r)
                red[kw][(lane >> 4)*4 + r][g*16 + (lane & 15)] = acc[g][r];
        __syncthreads();
        if (threadIdx.x < NG*64) {
            const int nb = jl * 4;
            f32x4 base = (KIH > 0) ? bias4 : p4;
            float gi = base[0] + red[0][b][nb+0] + red[1][b][nb+0] + red[2][b][nb+0] + red[3][b][nb+0];
            float gf = base[1] + red[0][b][nb+1] + red[1][b][nb+1] + red[2][b][nb+1] + red[3][b][nb+1];
            float gg = base[2] + red[0][b][nb+2] + red[1][b][nb+2] + red[2][b][nb+2] + red[3][b][nb+2];
            float go = base[3] + red[0][b][nb+3] + red[1][b][nb+3] + red[2][b][nb+3] + red[3][b][nb+3];
            float c = sigm(gf) * cst[b][jl] + sigm(gi) * ftanh(gg);
            float h = sigm(go) * ftanh(c);
            cst[b][jl] = c;
            const int j = (n0 >> 2) + jl;
            st2c(hseq + (size_t)(t+1)*SLO + b*HpHH + j, (f16)h);   // write-through
            if (l3) xs3[(size_t)(b*TT + t)*416 + j] = (f16)h;
            if (t == TT-1 && j < H) { hout[b*H + j] = h; cout[b*H + j] = c; }
            asm volatile("s_waitcnt vmcnt(0)" ::: "memory");       // h at LLC
        }
        __syncthreads();                                           // all waves drained
        if (threadIdx.x == 0)
            __hip_atomic_fetch_add(cown + (size_t)(t+1)*16, 1u,
                                   __ATOMIC_RELAXED, __HIP_MEMORY_SCOPE_AGENT);
    }
}

__global__ __launch_bounds__(256, 1) void lstm_mega(
    const float* __restrict__ pre1,
    const float* __restrict__ bias2, const float* __restrict__ bias3,
    const f16* __restrict__ whh1,
    const f16* __restrict__ wih2, const f16* __restrict__ whh2,
    const f16* __restrict__ wih3, const f16* __restrict__ whh3,
    f16* hs1, f16* hs2, f16* hs3,
    f16* xs3,
    float* h1o, float* c1o, float* h2o, float* c2o, float* h3o, float* c3o,
    unsigned* cnt1, unsigned* cnt2, unsigned* cnt3)
{
    __shared__ float red[4][16][66];   // stride 66: breaks bank aliasing
    __shared__ float cst[16][16];
    const int bx = blockIdx.x;
    if (bx < NWG1) {
        lstm_role<0,9,4>(red, cst, pre1, nullptr, nullptr, whh1,
                         nullptr, hs1, nullptr, h1o, c1o,
                         nullptr, cnt1, 0, NWG1, bx, HH, 0);
    } else if (bx < NWG1 + NWG2) {
        lstm_role<9,9,2>(red, cst, nullptr, bias2, wih2, whh2,
                         hs1, hs2, nullptr, h2o, c2o,
                         cnt1, cnt2, NWG1, NWG2, bx - NWG1, HH, 0);
    } else {
        lstm_role<9,4,4>(red, cst, nullptr, bias3, wih3, whh3,
                         hs2, hs3, xs3, h3o, c3o,
                         cnt2, cnt3, NWG2, NWG3, bx - NWG1 - NWG2, EE, 1);
    }
}

// ---------------- host ----------------
extern "C" void kernel_launch(void* const* d_in, const int* in_sizes, int n_in,
                              void* d_out, int out_size, void* d_ws, size_t ws_size,
                              hipStream_t stream)
{
    const float* emb  = (const float*)d_in[0];
    const float* Wih1 = (const float*)d_in[1];
    const float* Whh1 = (const float*)d_in[2];
    const float* bih1 = (const float*)d_in[3];
    const float* bhh1 = (const float*)d_in[4];
    const float* Wih2 = (const float*)d_in[5];
    const float* Whh2 = (const float*)d_in[6];
    const float* bih2 = (const float*)d_in[7];
    const float* bhh2 = (const float*)d_in[8];
    const float* Wih3 = (const float*)d_in[9];
    const float* Whh3 = (const float*)d_in[10];
    const float* bih3 = (const float*)d_in[11];
    const float* bhh3 = (const float*)d_in[12];
    const float* linb = (const float*)d_in[13];
    const int*   x    = (const int*)d_in[14];
    float* out = (float*)d_out;
    char*  ws  = (char*)d_ws;
    char*  outc = (char*)d_out;

    // ---- ws layout: counters (zeroed) + packed staging ----
    const size_t CNT1 = 0, CNT2 = 8320, CNT3 = 16640;   // 130 slots * 64 B each
    const size_t ZEND = 25088;
    size_t off = ZEND;
    auto alloc = [&](size_t bytes){ size_t r = off; off += (bytes + 255) & ~(size_t)255; return r; };
    const size_t EMBBF = alloc((size_t)VV*416*2);   // 26.6 MB
    const size_t XS0   = alloc((size_t)MM*416*2);   // embedded input, f16
    const size_t XS3   = alloc((size_t)MM*416*2);   // layer3 output, f16
    const size_t WIH1  = alloc((size_t)4608*416*2); // packed for pre-GEMM
    const size_t B1    = alloc((size_t)4608*4);
    const size_t B2    = alloc((size_t)4608*4);
    const size_t B3    = alloc((size_t)1664*4);

    f16* emb_bf = (f16*)(ws + EMBBF);
    f16* xs0    = (f16*)(ws + XS0);
    f16* xs3    = (f16*)(ws + XS3);
    f16* wih1p  = (f16*)(ws + WIH1);
    float* bias1 = (float*)(ws + B1);
    float* bias2 = (float*)(ws + B2);
    float* bias3 = (float*)(ws + B3);
    unsigned* cnt1 = (unsigned*)(ws + CNT1);
    unsigned* cnt2 = (unsigned*)(ws + CNT2);
    unsigned* cnt3 = (unsigned*)(ws + CNT3);

    // ---- big scratch lives in the (dead-until-final-GEMM) out buffer ----
    float* pre1 = out;                               // 2048*4608*4 = 37,748,736 B
    const size_t OW_HH1 = 37748736;                  // 4608*1152*2 = 10,616,832
    const size_t OW_IH2 = OW_HH1 + 10616832;
    const size_t OW_HH2 = OW_IH2 + 10616832;
    const size_t OW_IH3 = OW_HH2 + 10616832;         // 1664*1152*2 = 3,833,856
    const size_t OW_HH3 = OW_IH3 + 3833856;          // 1664*512*2  = 1,703,936
    const size_t HS1   = 75137024;                   // 129*16*1152*2 = 4,755,456
    const size_t HS2   = HS1 + 4755456;
    const size_t HS3   = HS2 + 4755456;              // 129*16*512*2 = 2,113,536 (end ~86.8 MB < 262 MB)
    f16* whh1p = (f16*)(outc + OW_HH1);
    f16* wih2p = (f16*)(outc + OW_IH2);
    f16* whh2p = (f16*)(outc + OW_HH2);
    f16* wih3p = (f16*)(outc + OW_IH3);
    f16* whh3p = (f16*)(outc + OW_HH3);
    f16* hs1   = (f16*)(outc + HS1);
    f16* hs2   = (f16*)(outc + HS2);
    f16* hs3   = (f16*)(outc + HS3);

    float* H1O = out + 65536000;  float* H2O = H1O + 18400;  float* H3O = H2O + 18400;
    float* C1O = H3O + 6400;      float* C2O = C1O + 18400;  float* C3O = C2O + 18400;

    hipMemsetAsync(d_ws, 0, ZEND, stream);          // counters
    hipMemsetAsync(outc + HS1, 0, 36864, stream);   // h1 slot 0 (zero init state)
    hipMemsetAsync(outc + HS2, 0, 36864, stream);   // h2 slot 0
    hipMemsetAsync(outc + HS3, 0, 16384, stream);   // h3 slot 0

    conv_emb    <<<dim3(2, VV), 256, 0, stream>>>(emb, emb_bf);
    embed_gather<<<dim3(2, MM), 256, 0, stream>>>(emb, x, xs0);

    // layer-1 input pre-GEMM (input known upfront; stays a throughput GEMM)
    conv_w   <<<dim3(2, 4608), 256, 0, stream>>>(Wih1, wih1p, HH, EE, 416);
    conv_bias<<<dim3(18),      256, 0, stream>>>(bih1, bhh1, bias1, HH, 4608);
    gemm16<0><<<dim3(36, 16),  256, 0, stream>>>(xs0, wih1p, bias1, pre1, 416, 4608);

    // pack all recurrent-phase weights/biases
    conv_w   <<<dim3(5, 4608), 256, 0, stream>>>(Whh1, whh1p, HH, HH, 1152);
    conv_w   <<<dim3(5, 4608), 256, 0, stream>>>(Wih2, wih2p, HH, HH, 1152);
    conv_w   <<<dim3(5, 4608), 256, 0, stream>>>(Whh2, whh2p, HH, HH, 1152);
    conv_w   <<<dim3(5, 1664), 256, 0, stream>>>(Wih3, wih3p, EE, HH, 1152);
    conv_w   <<<dim3(2, 1664), 256, 0, stream>>>(Whh3, whh3p, EE, EE, 512);
    conv_bias<<<dim3(18),      256, 0, stream>>>(bih2, bhh2, bias2, HH, 4608);
    conv_bias<<<dim3(7),       256, 0, stream>>>(bih3, bhh3, bias3, EE, 1664);

    // dataflow-synchronized 3-layer recurrence (no global barrier, no fences)
    lstm_mega<<<dim3(NWGT), 256, 0, stream>>>(
        pre1, bias2, bias3, whh1p, wih2p, whh2p, wih3p, whh3p,
        hs1, hs2, hs3,
        xs3, H1O, C1O, H2O, C2O, H3O, C3O, cnt1, cnt2, cnt3);

    // tied-weight logits with fused transpose to (B,V,T)
    gemm16<1><<<dim3(250, 16), 256, 0, stream>>>(xs3, emb_bf, linb, out, 416, 0);
}